// Round 5
// baseline (608.896 us; speedup 1.0000x reference)
//
#include <hip/hip_runtime.h>

#define B_  4
#define S_  2048
#define NX_ 1024
#define H_  16
#define D_  64
#define P_  512
#define NS_ 2560   // P + S
#define BHND_ ((size_t)B_*H_*NS_*D_)   // 10,485,760

#define QSCALE_ 0.18033688011112042f   // 0.125 * log2(e)
#define MASKC_  -14426.950408889634f   // -10000 * log2(e)

typedef __attribute__((ext_vector_type(8))) short bf16x8;
typedef __attribute__((ext_vector_type(4))) float f32x4;
typedef __attribute__((ext_vector_type(4))) float float4v;
typedef __attribute__((ext_vector_type(4))) unsigned short ushort4v;
typedef __attribute__((ext_vector_type(4))) unsigned int u32x4;

__device__ __forceinline__ unsigned short f2bf(float f){
  union { float f; unsigned u; } v; v.f = f;
  unsigned r = v.u + 0x7FFFu + ((v.u >> 16) & 1u);
  return (unsigned short)(r >> 16);
}

// pack two f32 -> u32 of 2 bf16 (RNE), lo = first arg
__device__ __forceinline__ unsigned cvtpk(float lo, float hi){
  unsigned r;
  asm("v_cvt_pk_bf16_f32 %0, %1, %2" : "=v"(r) : "v"(lo), "v"(hi));
  return r;
}

__device__ __forceinline__ void gll16(const void* g, void* l){
  __builtin_amdgcn_global_load_lds(
      (const __attribute__((address_space(1))) unsigned int*)g,
      (__attribute__((address_space(3))) unsigned int*)l, 16, 0, 0);
}

// barrier that drains LDS ops but leaves global (prefetch) loads in flight
__device__ __forceinline__ void bar_nodrain(){
  __builtin_amdgcn_sched_barrier(0);
  asm volatile("s_waitcnt lgkmcnt(0)" ::: "memory");
  __builtin_amdgcn_s_barrier();
  __builtin_amdgcn_sched_barrier(0);
}

// ---------------------------------------------------------------- prep kernels

__global__ void cvt_f32_bf16(const float* __restrict__ in, unsigned short* __restrict__ out, int n4){
  for (int i = blockIdx.x*blockDim.x + threadIdx.x; i < n4; i += gridDim.x*blockDim.x){
    float4v v = ((const float4v*)in)[i];
    ushort4v u = { f2bf(v.x), f2bf(v.y), f2bf(v.z), f2bf(v.w) };
    ((ushort4v*)out)[i] = u;
  }
}

// out[n][k] = bf16(in[k][n]); in: [K][N] f32
__global__ void transpose_cvt(const float* __restrict__ in, unsigned short* __restrict__ out, int K, int N){
  __shared__ float tile[32][33];
  int n0 = blockIdx.x*32, k0 = blockIdx.y*32;
  int tx = threadIdx.x & 31, ty = threadIdx.x >> 5;   // 256 thr = 32x8
  #pragma unroll
  for (int r = 0; r < 32; r += 8)
    tile[ty + r][tx] = in[(size_t)(k0 + ty + r)*N + n0 + tx];
  __syncthreads();
  #pragma unroll
  for (int r = 0; r < 32; r += 8)
    out[(size_t)(n0 + ty + r)*K + k0 + tx] = f2bf(tile[tx][ty + r]);
}

// layer_past [2][B][H][512][64] f32 -> present positions 0..511 (f32 passthrough, exact)
__global__ void past_kernel(const float* __restrict__ past, float* __restrict__ present){
  const int total4 = 2*B_*H_*P_*D_/4;  // 1,048,576 float4s
  for (int i = blockIdx.x*blockDim.x + threadIdx.x; i < total4; i += gridDim.x*blockDim.x){
    int d4  = i & 15;
    int pos = (i >> 4) & 511;
    int h   = (i >> 13) & 15;
    int b   = (i >> 17) & 3;
    int kv  = i >> 19;
    float4v v = ((const float4v*)past)[i];
    size_t off = (((size_t)(b*H_ + h))*NS_ + pos)*D_ + d4*4;
    ((float4v*)present)[((size_t)kv*BHND_ + off) >> 2] = v;
  }
}

// ---------------------------------------------------------------- GEMM (m97-style 128x128, BK=32)
template<int EPI>
__global__ __launch_bounds__(256, 2) void gemm_bf16(
    const unsigned short* __restrict__ A,
    const unsigned short* __restrict__ Bt,
    const float* __restrict__ bias,
    const int K, const int N,
    float* __restrict__ out_f32,
    unsigned short* __restrict__ out_q,
    float* __restrict__ present)
{
  __shared__ unsigned short As[128*32];  // 8 KB, [m][k] linear, 64B rows
  __shared__ unsigned short Bs[128*32];
  const int bm = blockIdx.x, bn = blockIdx.y;
  const int tid = threadIdx.x, lane = tid & 63, w = tid >> 6;
  const int wr = w >> 1, wc = w & 1;
  const int g = lane >> 4, li = lane & 15;
  f32x4 acc[4][4] = {};
  const char* Ab = (const char*)A + (size_t)(bm*128)*(K*2);
  const char* Bb = (const char*)Bt + (size_t)(bn*128)*(K*2);

  for (int kt = 0; kt < K; kt += 32){
    #pragma unroll
    for (int c = 0; c < 2; ++c){
      int off = c*4096 + w*1024 + lane*16;  // linear byte offset in 8KB tile
      int row = off >> 6, col = off & 63;
      gll16(Ab + (size_t)row*(K*2) + (size_t)kt*2 + col, (char*)As + c*4096 + w*1024);
      gll16(Bb + (size_t)row*(K*2) + (size_t)kt*2 + col, (char*)Bs + c*4096 + w*1024);
    }
    __syncthreads();
    bf16x8 af[4], bfr[4];
    #pragma unroll
    for (int mf = 0; mf < 4; ++mf)
      af[mf] = *(const bf16x8*)((const char*)As + (wr*64 + mf*16 + li)*64 + g*16);
    #pragma unroll
    for (int nf = 0; nf < 4; ++nf)
      bfr[nf] = *(const bf16x8*)((const char*)Bs + (wc*64 + nf*16 + li)*64 + g*16);
    #pragma unroll
    for (int mf = 0; mf < 4; ++mf)
      #pragma unroll
      for (int nf = 0; nf < 4; ++nf)
        acc[mf][nf] = __builtin_amdgcn_mfma_f32_16x16x32_bf16(af[mf], bfr[nf], acc[mf][nf], 0, 0, 0);
    __syncthreads();
  }

  #pragma unroll
  for (int mf = 0; mf < 4; ++mf){
    #pragma unroll
    for (int nf = 0; nf < 4; ++nf){
      int n = bn*128 + wc*64 + nf*16 + li;
      float bsv = bias[n];
      #pragma unroll
      for (int r = 0; r < 4; ++r){
        int m = bm*128 + wr*64 + mf*16 + g*4 + r;
        float v = acc[mf][nf][r] + bsv;
        if (EPI == 0){
          int b = m >> 11, sI = m & 2047;
          if (n < 1024){
            int hh = n >> 6, d = n & 63;
            out_q[(((size_t)(b*H_ + hh)*S_ + sI) << 6) + d] = f2bf(v * QSCALE_);
          } else {
            int cc = n & 1023; int hh = cc >> 6, d = cc & 63;
            size_t off = (((size_t)(b*H_ + hh)*NS_ + P_ + sI) << 6) + d;
            present[(n < 2048 ? (size_t)0 : BHND_) + off] = v;
          }
        } else {
          out_f32[(size_t)m*N + n] = v;
        }
      }
    }
  }
}

// ---------------------------------------------------------------- flash attention
// grid (64 bh, 16 supertiles); 256 threads = 4 waves x 32 q-rows = 128-row supertile.
// qsup = 15 - blockIdx.y so longest blocks dispatch first (LPT balance, ~4 blocks/CU).
// kv-permuted P/V layout: short idx = 2*li + (cf&1) + 32*(cf>>1); V slot j holds
// (kv_lo = (j&15)+32*(j>>4), kv_hi = kv_lo+16) packed in one u32. P and V use the
// same permutation so PV is invariant. l-row accumulated via MFMA with ones-B.
__global__ __launch_bounds__(256, 4) void attn_kernel(
    const unsigned short* __restrict__ Qb,   // [B*H][2048][64] bf16, pre-scaled by QSCALE_
    const float* __restrict__ presK,         // [B*H][2560][64] f32
    const float* __restrict__ presV,         // [B*H][2560][64] f32
    unsigned short* __restrict__ Aout)       // [B][2048][1024] bf16
{
  __shared__ unsigned short Klds[64*64];     // 8 KB, XOR-swizzled rows (128B)
  __shared__ unsigned short Vt[64*72];       // [d][kv-slots], row stride 144B
  __shared__ unsigned short Plds[4][32*72];  // per-wave [q][kv-permuted], 144B rows

  const int bh = blockIdx.x;
  const int qsup = 15 - (int)blockIdx.y;
  const int tid = threadIdx.x, lane = tid & 63, w = tid >> 6;
  const int g = lane >> 4, li = lane & 15;
  const int q0w = qsup*128 + w*32;
  const int nt = 2*qsup + 10;

  // staging coords (256 threads)
  const int krow = tid >> 2, kq16 = tid & 3;             // K: row, 16-float chunk
  const int vslot = tid & 31, vd0 = (tid >> 5) << 3;     // V: u32 slot, 8 d-values
  const int vkv_lo = (vslot & 15) + ((vslot >> 4) << 5); // slot -> (kv_lo, kv_lo+16)

  const float* Kbase = presK + (((size_t)bh*NS_) << 6);
  const float* Vbase = presV + (((size_t)bh*NS_) << 6);
  const int b = bh >> 4, h = bh & 15;

  // Q fragments: rows q0w+rf*16+li, k-slices of 8
  bf16x8 qf[2][2];
  #pragma unroll
  for (int rf = 0; rf < 2; ++rf)
    #pragma unroll
    for (int ks = 0; ks < 2; ++ks)
      qf[rf][ks] = *(const bf16x8*)(Qb + (((size_t)bh*S_ + q0w + rf*16 + li) << 6) + ks*32 + g*8);

  // ones B-fragment for l-row MFMA
  bf16x8 ones;
  #pragma unroll
  for (int j = 0; j < 8; ++j) ones[j] = (short)0x3F80;

  f32x4 o[2][4];
  f32x4 lacc[2];
  float mrow[2][4];
  #pragma unroll
  for (int rf = 0; rf < 2; ++rf){
    #pragma unroll
    for (int df = 0; df < 4; ++df) o[rf][df] = (f32x4){0.f,0.f,0.f,0.f};
    lacc[rf] = (f32x4){0.f,0.f,0.f,0.f};
    #pragma unroll
    for (int r = 0; r < 4; ++r) mrow[rf][r] = -1e30f;
  }

  // prologue: raw f32 loads for tile 0
  float4v kraw[4], vraw[4];
  {
    const float* kp = Kbase + ((size_t)krow << 6) + kq16*16;
    #pragma unroll
    for (int j = 0; j < 4; ++j) kraw[j] = ((const float4v*)kp)[j];
    const float* vl = Vbase + ((size_t)vkv_lo << 6) + vd0;
    vraw[0] = ((const float4v*)vl)[0]; vraw[1] = ((const float4v*)vl)[1];
    const float* vh = vl + (16 << 6);
    vraw[2] = ((const float4v*)vh)[0]; vraw[3] = ((const float4v*)vh)[1];
  }

  #pragma unroll 1
  for (int t = 0; t < nt; ++t){
    // convert raw -> packed bf16 u32 (vmcnt wait lands here, loads had full compute to arrive)
    unsigned ku[8], vu[8];
    {
      const float* kf = (const float*)kraw;
      #pragma unroll
      for (int j = 0; j < 8; ++j) ku[j] = cvtpk(kf[2*j], kf[2*j+1]);
      const float* vlo = (const float*)&vraw[0];
      const float* vhi = (const float*)&vraw[2];
      #pragma unroll
      for (int j = 0; j < 8; ++j) vu[j] = cvtpk(vlo[j], vhi[j]);
    }

    bar_nodrain();   // prev tile's LDS reads done; prefetch loads unaffected
    // --- stage K (XOR-swizzled two b128 writes) ---
    {
      int sw = (krow & 7) << 4;
      char* kb = (char*)Klds + krow*128;
      *(u32x4*)(kb + ((kq16*32) ^ sw))      = (u32x4){ku[0],ku[1],ku[2],ku[3]};
      *(u32x4*)(kb + ((kq16*32 + 16) ^ sw)) = (u32x4){ku[4],ku[5],ku[6],ku[7]};
    }
    // --- stage V (permuted kv-pair slots, 8 b32 writes) ---
    #pragma unroll
    for (int j = 0; j < 8; ++j)
      *(unsigned*)((char*)Vt + (size_t)(vd0 + j)*144 + vslot*4) = vu[j];
    // --- prefetch raw tile t+1 ---
    if (t + 1 < nt){
      const float* kp = Kbase + ((size_t)((t+1)*64 + krow) << 6) + kq16*16;
      #pragma unroll
      for (int j = 0; j < 4; ++j) kraw[j] = ((const float4v*)kp)[j];
      const float* vl = Vbase + ((size_t)((t+1)*64 + vkv_lo) << 6) + vd0;
      vraw[0] = ((const float4v*)vl)[0]; vraw[1] = ((const float4v*)vl)[1];
      const float* vh = vl + (16 << 6);
      vraw[2] = ((const float4v*)vh)[0]; vraw[3] = ((const float4v*)vh)[1];
    }
    bar_nodrain();   // staged LDS visible; prefetch stays in flight

    const int kbase = t*64;
    if (kbase <= q0w + 543){                      // wave has any unmasked key in this tile
      const bool needmask = (kbase + 63) > (q0w + 512);

      // --- S = Q K^T (log2-scaled since Q pre-scaled) ---
      f32x4 s[2][4];
      #pragma unroll
      for (int cf = 0; cf < 4; ++cf){
        int row = cf*16 + li;
        int sw = (row & 7) << 4;
        const char* kb = (const char*)Klds + row*128;
        bf16x8 bk0 = *(const bf16x8*)(kb + ((g*16) ^ sw));
        bf16x8 bk1 = *(const bf16x8*)(kb + ((64 + g*16) ^ sw));
        #pragma unroll
        for (int rf = 0; rf < 2; ++rf){
          f32x4 a0 = (f32x4){0.f,0.f,0.f,0.f};
          a0 = __builtin_amdgcn_mfma_f32_16x16x32_bf16(qf[rf][0], bk0, a0, 0, 0, 0);
          a0 = __builtin_amdgcn_mfma_f32_16x16x32_bf16(qf[rf][1], bk1, a0, 0, 0, 0);
          s[rf][cf] = a0;
        }
      }

      #pragma unroll
      for (int rf = 0; rf < 2; ++rf){
        float pm[4];
        #pragma unroll
        for (int r = 0; r < 4; ++r){
          if (needmask){
            int q = q0w + rf*16 + g*4 + r;
            int lim = q + 512 - kbase;            // key_local <= lim allowed
            #pragma unroll
            for (int cf = 0; cf < 4; ++cf){
              int kl = cf*16 + li;
              s[rf][cf][r] = (kl <= lim) ? s[rf][cf][r] : MASKC_;
            }
          }
          pm[r] = fmaxf(fmaxf(s[rf][0][r], s[rf][1][r]), fmaxf(s[rf][2][r], s[rf][3][r]));
        }
        #pragma unroll
        for (int r = 0; r < 4; ++r)
          #pragma unroll
          for (int d2 = 1; d2 < 16; d2 <<= 1)
            pm[r] = fmaxf(pm[r], __shfl_xor(pm[r], d2, 64));

        // defer-max: only rescale when max grew by > 8 (log2 domain, P <= 256)
        bool grow = (pm[0] > mrow[rf][0] + 8.f) | (pm[1] > mrow[rf][1] + 8.f) |
                    (pm[2] > mrow[rf][2] + 8.f) | (pm[3] > mrow[rf][3] + 8.f);
        if (__ballot(grow)){
          #pragma unroll
          for (int r = 0; r < 4; ++r){
            float mn = fmaxf(mrow[rf][r], pm[r]);
            float al = __builtin_amdgcn_exp2f(mrow[rf][r] - mn);
            mrow[rf][r] = mn;
            #pragma unroll
            for (int df = 0; df < 4; ++df) o[rf][df][r] *= al;
            lacc[rf][r] *= al;
          }
        }

        // P = exp2(S - m), packed pairs (cf,cf+1) -> permuted layout
        #pragma unroll
        for (int r = 0; r < 4; ++r){
          float p0 = __builtin_amdgcn_exp2f(s[rf][0][r] - mrow[rf][r]);
          float p1 = __builtin_amdgcn_exp2f(s[rf][1][r] - mrow[rf][r]);
          float p2 = __builtin_amdgcn_exp2f(s[rf][2][r] - mrow[rf][r]);
          float p3 = __builtin_amdgcn_exp2f(s[rf][3][r] - mrow[rf][r]);
          char* prow = (char*)Plds[w] + (size_t)(rf*16 + g*4 + r)*144 + li*4;
          *(unsigned*)prow        = cvtpk(p0, p1);
          *(unsigned*)(prow + 64) = cvtpk(p2, p3);
        }
      }

      // --- O += P V ;  l += P * ones  (MFMA pipe) ---
      bf16x8 bv[4][2];
      #pragma unroll
      for (int df = 0; df < 4; ++df){
        bv[df][0] = *(const bf16x8*)(Vt + (df*16 + li)*72 + g*8);
        bv[df][1] = *(const bf16x8*)(Vt + (df*16 + li)*72 + 32 + g*8);
      }
      #pragma unroll
      for (int rf = 0; rf < 2; ++rf){
        bf16x8 pa0 = *(const bf16x8*)(Plds[w] + (rf*16 + li)*72 + g*8);
        bf16x8 pa1 = *(const bf16x8*)(Plds[w] + (rf*16 + li)*72 + 32 + g*8);
        #pragma unroll
        for (int df = 0; df < 4; ++df){
          o[rf][df] = __builtin_amdgcn_mfma_f32_16x16x32_bf16(pa0, bv[df][0], o[rf][df], 0, 0, 0);
          o[rf][df] = __builtin_amdgcn_mfma_f32_16x16x32_bf16(pa1, bv[df][1], o[rf][df], 0, 0, 0);
        }
        lacc[rf] = __builtin_amdgcn_mfma_f32_16x16x32_bf16(pa0, ones, lacc[rf], 0, 0, 0);
        lacc[rf] = __builtin_amdgcn_mfma_f32_16x16x32_bf16(pa1, ones, lacc[rf], 0, 0, 0);
      }
    }
  }

  #pragma unroll
  for (int rf = 0; rf < 2; ++rf){
    float inv[4];
    #pragma unroll
    for (int r = 0; r < 4; ++r) inv[r] = 1.0f / lacc[rf][r];
    #pragma unroll
    for (int df = 0; df < 4; ++df)
      #pragma unroll
      for (int r = 0; r < 4; ++r){
        int q = q0w + rf*16 + g*4 + r;
        Aout[((size_t)b*S_ + q)*NX_ + h*64 + df*16 + li] = f2bf(o[rf][df][r]*inv[r]);
      }
  }
}

// ---------------------------------------------------------------- launch

extern "C" void kernel_launch(void* const* d_in, const int* in_sizes, int n_in,
                              void* d_out, int out_size, void* d_ws, size_t ws_size,
                              hipStream_t stream){
  const float* x          = (const float*)d_in[0];
  const float* layer_past = (const float*)d_in[1];
  const float* c_attn_w   = (const float*)d_in[2];
  const float* c_attn_b   = (const float*)d_in[3];
  const float* c_proj_w   = (const float*)d_in[4];
  const float* c_proj_b   = (const float*)d_in[5];

  float* out = (float*)d_out;
  float* present = out + (size_t)B_*S_*NX_;   // a is [B,S,NX] = 8,388,608 f32
  float* presK = present;
  float* presV = present + BHND_;

  // workspace: 20,971,520 shorts = 41.9 MiB total
  unsigned short* ws = (unsigned short*)d_ws;
  unsigned short* xb     = ws;                              // 8,388,608 (reused as Ab after gemm<0>)
  unsigned short* wqkvT  = xb     + (size_t)8388608;        // 3,145,728  [3072][1024]
  unsigned short* wprojT = wqkvT  + (size_t)3145728;        // 1,048,576  [1024][1024]
  unsigned short* Qb     = wprojT + (size_t)1048576;        // 8,388,608  [B*H][2048][64]
  unsigned short* Ab     = xb;                              // alias: xb dead after gemm<0>

  cvt_f32_bf16<<<2048, 256, 0, stream>>>(x, xb, (int)(8388608/4));
  transpose_cvt<<<dim3(3072/32, 1024/32), 256, 0, stream>>>(c_attn_w, wqkvT, 1024, 3072);
  transpose_cvt<<<dim3(1024/32, 1024/32), 256, 0, stream>>>(c_proj_w, wprojT, 1024, 1024);
  past_kernel<<<2048, 256, 0, stream>>>(layer_past, present);

  gemm_bf16<0><<<dim3(64, 24), 256, 0, stream>>>(xb, wqkvT, c_attn_b, 1024, 3072,
                                                 nullptr, Qb, present);
  attn_kernel<<<dim3(64, 16), 256, 0, stream>>>(Qb, presK, presV, Ab);
  gemm_bf16<1><<<dim3(64, 8), 256, 0, stream>>>(Ab, wprojT, c_proj_b, 1024, 1024,
                                                out, nullptr, nullptr);
}

// Round 6
// 473.226 us; speedup vs baseline: 1.2867x; 1.2867x over previous
//
#include <hip/hip_runtime.h>

#define B_  4
#define S_  2048
#define NX_ 1024
#define H_  16
#define D_  64
#define P_  512
#define NS_ 2560   // P + S
#define BHND_ ((size_t)B_*H_*NS_*D_)   // 10,485,760

#define QSCALE_ 0.18033688011112042f   // 0.125 * log2(e)
#define MASKC_  -14426.950408889634f   // -10000 * log2(e)

typedef __attribute__((ext_vector_type(8))) short bf16x8;
typedef __attribute__((ext_vector_type(4))) float f32x4;
typedef __attribute__((ext_vector_type(4))) float float4v;
typedef __attribute__((ext_vector_type(4))) unsigned short ushort4v;
typedef __attribute__((ext_vector_type(4))) unsigned int u32x4;

__device__ __forceinline__ unsigned short f2bf(float f){
  union { float f; unsigned u; } v; v.f = f;
  unsigned r = v.u + 0x7FFFu + ((v.u >> 16) & 1u);
  return (unsigned short)(r >> 16);
}

// pack two f32 -> u32 of 2 bf16 (RNE), lo = first arg
__device__ __forceinline__ unsigned cvtpk(float lo, float hi){
  unsigned r;
  asm("v_cvt_pk_bf16_f32 %0, %1, %2" : "=v"(r) : "v"(lo), "v"(hi));
  return r;
}

__device__ __forceinline__ void gll16(const void* g, void* l){
  __builtin_amdgcn_global_load_lds(
      (const __attribute__((address_space(1))) unsigned int*)g,
      (__attribute__((address_space(3))) unsigned int*)l, 16, 0, 0);
}

// barrier that drains LDS ops but leaves global (prefetch) loads in flight
__device__ __forceinline__ void bar_nodrain(){
  __builtin_amdgcn_sched_barrier(0);
  asm volatile("s_waitcnt lgkmcnt(0)" ::: "memory");
  __builtin_amdgcn_s_barrier();
  __builtin_amdgcn_sched_barrier(0);
}

// ---------------------------------------------------------------- prep kernels

__global__ void cvt_f32_bf16(const float* __restrict__ in, unsigned short* __restrict__ out, int n4){
  for (int i = blockIdx.x*blockDim.x + threadIdx.x; i < n4; i += gridDim.x*blockDim.x){
    float4v v = ((const float4v*)in)[i];
    ushort4v u = { f2bf(v.x), f2bf(v.y), f2bf(v.z), f2bf(v.w) };
    ((ushort4v*)out)[i] = u;
  }
}

// out[n][k] = bf16(in[k][n]); in: [K][N] f32
__global__ void transpose_cvt(const float* __restrict__ in, unsigned short* __restrict__ out, int K, int N){
  __shared__ float tile[32][33];
  int n0 = blockIdx.x*32, k0 = blockIdx.y*32;
  int tx = threadIdx.x & 31, ty = threadIdx.x >> 5;   // 256 thr = 32x8
  #pragma unroll
  for (int r = 0; r < 32; r += 8)
    tile[ty + r][tx] = in[(size_t)(k0 + ty + r)*N + n0 + tx];
  __syncthreads();
  #pragma unroll
  for (int r = 0; r < 32; r += 8)
    out[(size_t)(n0 + ty + r)*K + k0 + tx] = f2bf(tile[tx][ty + r]);
}

// layer_past -> present positions 0..511 (f32 exact) + Kb bf16 (K half only)
__global__ void past_kernel(const float* __restrict__ past, float* __restrict__ present,
                            unsigned short* __restrict__ Kb){
  const int total4 = 2*B_*H_*P_*D_/4;  // 1,048,576 float4s
  for (int i = blockIdx.x*blockDim.x + threadIdx.x; i < total4; i += gridDim.x*blockDim.x){
    int d4  = i & 15;
    int pos = (i >> 4) & 511;
    int h   = (i >> 13) & 15;
    int b   = (i >> 17) & 3;
    int kv  = i >> 19;
    float4v v = ((const float4v*)past)[i];
    size_t off = (((size_t)(b*H_ + h))*NS_ + pos)*D_ + d4*4;
    ((float4v*)present)[((size_t)kv*BHND_ + off) >> 2] = v;
    if (!kv){
      ushort4v u = { f2bf(v.x), f2bf(v.y), f2bf(v.z), f2bf(v.w) };
      ((ushort4v*)Kb)[off >> 2] = u;
    }
  }
}

// ---------------------------------------------------------------- GEMM (m97-style 128x128, BK=32)
template<int EPI>
__global__ __launch_bounds__(256, 2) void gemm_bf16(
    const unsigned short* __restrict__ A,
    const unsigned short* __restrict__ Bt,
    const float* __restrict__ bias,
    const int K, const int N,
    float* __restrict__ out_f32,
    unsigned short* __restrict__ out_q,
    unsigned short* __restrict__ out_k,
    float* __restrict__ present)
{
  __shared__ unsigned short As[128*32];  // 8 KB, [m][k] linear, 64B rows
  __shared__ unsigned short Bs[128*32];
  const int bm = blockIdx.x, bn = blockIdx.y;
  const int tid = threadIdx.x, lane = tid & 63, w = tid >> 6;
  const int wr = w >> 1, wc = w & 1;
  const int g = lane >> 4, li = lane & 15;
  f32x4 acc[4][4] = {};
  const char* Ab = (const char*)A + (size_t)(bm*128)*(K*2);
  const char* Bb = (const char*)Bt + (size_t)(bn*128)*(K*2);

  for (int kt = 0; kt < K; kt += 32){
    #pragma unroll
    for (int c = 0; c < 2; ++c){
      int off = c*4096 + w*1024 + lane*16;  // linear byte offset in 8KB tile
      int row = off >> 6, col = off & 63;
      gll16(Ab + (size_t)row*(K*2) + (size_t)kt*2 + col, (char*)As + c*4096 + w*1024);
      gll16(Bb + (size_t)row*(K*2) + (size_t)kt*2 + col, (char*)Bs + c*4096 + w*1024);
    }
    __syncthreads();
    bf16x8 af[4], bfr[4];
    #pragma unroll
    for (int mf = 0; mf < 4; ++mf)
      af[mf] = *(const bf16x8*)((const char*)As + (wr*64 + mf*16 + li)*64 + g*16);
    #pragma unroll
    for (int nf = 0; nf < 4; ++nf)
      bfr[nf] = *(const bf16x8*)((const char*)Bs + (wc*64 + nf*16 + li)*64 + g*16);
    #pragma unroll
    for (int mf = 0; mf < 4; ++mf)
      #pragma unroll
      for (int nf = 0; nf < 4; ++nf)
        acc[mf][nf] = __builtin_amdgcn_mfma_f32_16x16x32_bf16(af[mf], bfr[nf], acc[mf][nf], 0, 0, 0);
    __syncthreads();
  }

  #pragma unroll
  for (int mf = 0; mf < 4; ++mf){
    #pragma unroll
    for (int nf = 0; nf < 4; ++nf){
      int n = bn*128 + wc*64 + nf*16 + li;
      float bsv = bias[n];
      #pragma unroll
      for (int r = 0; r < 4; ++r){
        int m = bm*128 + wr*64 + mf*16 + g*4 + r;
        float v = acc[mf][nf][r] + bsv;
        if (EPI == 0){
          int b = m >> 11, sI = m & 2047;
          if (n < 1024){
            int hh = n >> 6, d = n & 63;
            out_q[(((size_t)(b*H_ + hh)*S_ + sI) << 6) + d] = f2bf(v * QSCALE_);
          } else {
            int cc = n & 1023; int hh = cc >> 6, d = cc & 63;
            size_t off = (((size_t)(b*H_ + hh)*NS_ + P_ + sI) << 6) + d;
            if (n < 2048){
              present[off] = v;
              out_k[off] = f2bf(v);
            } else {
              present[BHND_ + off] = v;
            }
          }
        } else {
          out_f32[(size_t)m*N + n] = v;
        }
      }
    }
  }
}

// ---------------------------------------------------------------- flash attention
// grid (16 sup, 64 bh); 256 threads = 4 waves x 32 q-rows; KV tile 64.
// qsup = 15 - blockIdx.x (LPT: longest first); supertile-fast dispatch keeps a bh's
// K/V hot in one XCD's L2. K bf16 via global_load_lds (pre-swizzled source, dbuf);
// V f32 reg-prefetched + cvt_pk. l-row via MFMA(ones). Defer-max (log2, THR=8).
__global__ __launch_bounds__(256, 3) void attn_kernel(
    const unsigned short* __restrict__ Qb,   // [B*H][2048][64] bf16, pre-scaled by QSCALE_
    const unsigned short* __restrict__ Kb,   // [B*H][2560][64] bf16
    const float* __restrict__ presV,         // [B*H][2560][64] f32
    unsigned short* __restrict__ Aout)       // [B][2048][1024] bf16
{
  __shared__ unsigned short Klds[2][64*64];  // 2 x 8 KB, XOR-swizzled rows (128B)
  __shared__ unsigned short Vt[64*72];       // [d][kv-slots], row stride 144B
  __shared__ unsigned short Plds[4][32*72];  // per-wave [q][kv-permuted], 144B rows

  const int qsup = 15 - (int)blockIdx.x;
  const int bh = blockIdx.y;
  const int tid = threadIdx.x, lane = tid & 63, w = tid >> 6;
  const int g = lane >> 4, li = lane & 15;
  const int q0w = qsup*128 + w*32;
  const int nt = 2*qsup + 10;

  // K gll staging: 2 chunks of 16B per thread, pre-swizzled global source
  const int koff0 = w*1024 + lane*16;            // c=0
  const int koff1 = 4096 + w*1024 + lane*16;     // c=1
  const char* KbB = (const char*)Kb + (((size_t)bh*NS_) << 7);
  const char* pK0 = KbB + (size_t)(koff0 >> 7)*128 + (((koff0 & 127) ^ (((koff0 >> 7) & 7) << 4)));
  const char* pK1 = KbB + (size_t)(koff1 >> 7)*128 + (((koff1 & 127) ^ (((koff1 >> 7) & 7) << 4)));
  const int kldsOff = w*1024 + (koff0 & 15);     // wave-uniform part handled below
  (void)kldsOff;

  // V staging coords
  const int vslot = tid & 31, vd0 = (tid >> 5) << 3;     // V: u32 slot, 8 d-values
  const int vkv_lo = (vslot & 15) + ((vslot >> 4) << 5); // slot -> (kv_lo, kv_lo+16)
  const float* Vbase = presV + (((size_t)bh*NS_) << 6);
  const int b = bh >> 4, h = bh & 15;

  // Q fragments: rows q0w+rf*16+li, k-slices of 8
  bf16x8 qf[2][2];
  #pragma unroll
  for (int rf = 0; rf < 2; ++rf)
    #pragma unroll
    for (int ks = 0; ks < 2; ++ks)
      qf[rf][ks] = *(const bf16x8*)(Qb + (((size_t)bh*S_ + q0w + rf*16 + li) << 6) + ks*32 + g*8);

  // ones B-fragment for l-row MFMA
  bf16x8 ones;
  #pragma unroll
  for (int j = 0; j < 8; ++j) ones[j] = (short)0x3F80;

  f32x4 o[2][4];
  f32x4 lacc[2];
  float mrow[2][4];
  #pragma unroll
  for (int rf = 0; rf < 2; ++rf){
    #pragma unroll
    for (int df = 0; df < 4; ++df) o[rf][df] = (f32x4){0.f,0.f,0.f,0.f};
    lacc[rf] = (f32x4){0.f,0.f,0.f,0.f};
    #pragma unroll
    for (int r = 0; r < 4; ++r) mrow[rf][r] = -1e30f;
  }

  // prologue: gll K(0) FIRST, then raw V(0) loads (vmcnt order => V-wait covers gll)
  float4v vraw[4];
  {
    gll16(pK0, (char*)Klds[0] + w*1024);
    gll16(pK1, (char*)Klds[0] + 4096 + w*1024);
    __builtin_amdgcn_sched_barrier(0);
    const float* vl = Vbase + ((size_t)vkv_lo << 6) + vd0;
    vraw[0] = ((const float4v*)vl)[0]; vraw[1] = ((const float4v*)vl)[1];
    const float* vh = vl + (16 << 6);
    vraw[2] = ((const float4v*)vh)[0]; vraw[3] = ((const float4v*)vh)[1];
  }

  #pragma unroll 1
  for (int t = 0; t < nt; ++t){
    const int cur = t & 1;
    // a) convert V raw -> packed bf16 (implicit vmcnt wait: also guarantees K gll landed)
    unsigned vu[8];
    {
      const float* vlo = (const float*)&vraw[0];
      const float* vhi = (const float*)&vraw[2];
      #pragma unroll
      for (int j = 0; j < 8; ++j) vu[j] = cvtpk(vlo[j], vhi[j]);
    }
    // b) prev tile's LDS reads done
    bar_nodrain();
    // c) stage V (permuted kv-pair slots, 8 b32 writes)
    #pragma unroll
    for (int j = 0; j < 8; ++j)
      *(unsigned*)((char*)Vt + (size_t)(vd0 + j)*144 + vslot*4) = vu[j];
    // d) issue next tile: K gll FIRST, then raw V loads
    if (t + 1 < nt){
      size_t adv = (size_t)(t + 1) * 8192;
      gll16(pK0 + adv, (char*)Klds[cur ^ 1] + w*1024);
      gll16(pK1 + adv, (char*)Klds[cur ^ 1] + 4096 + w*1024);
      __builtin_amdgcn_sched_barrier(0);
      const float* vl = Vbase + ((size_t)((t+1)*64 + vkv_lo) << 6) + vd0;
      vraw[0] = ((const float4v*)vl)[0]; vraw[1] = ((const float4v*)vl)[1];
      const float* vh = vl + (16 << 6);
      vraw[2] = ((const float4v*)vh)[0]; vraw[3] = ((const float4v*)vh)[1];
    }
    // e) staged LDS visible; next-tile loads stay in flight
    bar_nodrain();

    const int kbase = t*64;
    if (kbase <= q0w + 543){                      // wave has any unmasked key in this tile
      const bool needmask = (kbase + 63) > (q0w + 512);

      // --- S = Q K^T (log2-scaled since Q pre-scaled) ---
      f32x4 s[2][4];
      #pragma unroll
      for (int cf = 0; cf < 4; ++cf){
        int row = cf*16 + li;
        int sw = (row & 7) << 4;
        const char* kb = (const char*)Klds[cur] + row*128;
        bf16x8 bk0 = *(const bf16x8*)(kb + ((g*16) ^ sw));
        bf16x8 bk1 = *(const bf16x8*)(kb + ((64 + g*16) ^ sw));
        #pragma unroll
        for (int rf = 0; rf < 2; ++rf){
          f32x4 a0 = (f32x4){0.f,0.f,0.f,0.f};
          a0 = __builtin_amdgcn_mfma_f32_16x16x32_bf16(qf[rf][0], bk0, a0, 0, 0, 0);
          a0 = __builtin_amdgcn_mfma_f32_16x16x32_bf16(qf[rf][1], bk1, a0, 0, 0, 0);
          s[rf][cf] = a0;
        }
      }

      #pragma unroll
      for (int rf = 0; rf < 2; ++rf){
        float pm[4];
        #pragma unroll
        for (int r = 0; r < 4; ++r){
          if (needmask){
            int q = q0w + rf*16 + g*4 + r;
            int lim = q + 512 - kbase;            // key_local <= lim allowed
            #pragma unroll
            for (int cf = 0; cf < 4; ++cf){
              int kl = cf*16 + li;
              s[rf][cf][r] = (kl <= lim) ? s[rf][cf][r] : MASKC_;
            }
          }
          pm[r] = fmaxf(fmaxf(s[rf][0][r], s[rf][1][r]), fmaxf(s[rf][2][r], s[rf][3][r]));
        }
        #pragma unroll
        for (int r = 0; r < 4; ++r)
          #pragma unroll
          for (int d2 = 1; d2 < 16; d2 <<= 1)
            pm[r] = fmaxf(pm[r], __shfl_xor(pm[r], d2, 64));

        // defer-max: only rescale when max grew by > 8 (log2 domain, P <= 256)
        bool grow = (pm[0] > mrow[rf][0] + 8.f) | (pm[1] > mrow[rf][1] + 8.f) |
                    (pm[2] > mrow[rf][2] + 8.f) | (pm[3] > mrow[rf][3] + 8.f);
        if (__ballot(grow)){
          #pragma unroll
          for (int r = 0; r < 4; ++r){
            float mn = fmaxf(mrow[rf][r], pm[r]);
            float al = __builtin_amdgcn_exp2f(mrow[rf][r] - mn);
            mrow[rf][r] = mn;
            #pragma unroll
            for (int df = 0; df < 4; ++df) o[rf][df][r] *= al;
            lacc[rf][r] *= al;
          }
        }

        // P = exp2(S - m), packed pairs -> permuted layout
        #pragma unroll
        for (int r = 0; r < 4; ++r){
          float p0 = __builtin_amdgcn_exp2f(s[rf][0][r] - mrow[rf][r]);
          float p1 = __builtin_amdgcn_exp2f(s[rf][1][r] - mrow[rf][r]);
          float p2 = __builtin_amdgcn_exp2f(s[rf][2][r] - mrow[rf][r]);
          float p3 = __builtin_amdgcn_exp2f(s[rf][3][r] - mrow[rf][r]);
          char* prow = (char*)Plds[w] + (size_t)(rf*16 + g*4 + r)*144 + li*4;
          *(unsigned*)prow        = cvtpk(p0, p1);
          *(unsigned*)(prow + 64) = cvtpk(p2, p3);
        }
      }

      // --- O += P V ;  l += P * ones  (MFMA pipe) ---
      bf16x8 bv[4][2];
      #pragma unroll
      for (int df = 0; df < 4; ++df){
        bv[df][0] = *(const bf16x8*)(Vt + (df*16 + li)*72 + g*8);
        bv[df][1] = *(const bf16x8*)(Vt + (df*16 + li)*72 + 32 + g*8);
      }
      #pragma unroll
      for (int rf = 0; rf < 2; ++rf){
        bf16x8 pa0 = *(const bf16x8*)(Plds[w] + (rf*16 + li)*72 + g*8);
        bf16x8 pa1 = *(const bf16x8*)(Plds[w] + (rf*16 + li)*72 + 32 + g*8);
        #pragma unroll
        for (int df = 0; df < 4; ++df){
          o[rf][df] = __builtin_amdgcn_mfma_f32_16x16x32_bf16(pa0, bv[df][0], o[rf][df], 0, 0, 0);
          o[rf][df] = __builtin_amdgcn_mfma_f32_16x16x32_bf16(pa1, bv[df][1], o[rf][df], 0, 0, 0);
        }
        lacc[rf] = __builtin_amdgcn_mfma_f32_16x16x32_bf16(pa0, ones, lacc[rf], 0, 0, 0);
        lacc[rf] = __builtin_amdgcn_mfma_f32_16x16x32_bf16(pa1, ones, lacc[rf], 0, 0, 0);
      }
    }
  }

  #pragma unroll
  for (int rf = 0; rf < 2; ++rf){
    float inv[4];
    #pragma unroll
    for (int r = 0; r < 4; ++r) inv[r] = 1.0f / lacc[rf][r];
    #pragma unroll
    for (int df = 0; df < 4; ++df)
      #pragma unroll
      for (int r = 0; r < 4; ++r){
        int q = q0w + rf*16 + g*4 + r;
        Aout[((size_t)b*S_ + q)*NX_ + h*64 + df*16 + li] = f2bf(o[rf][df][r]*inv[r]);
      }
  }
}

// ---------------------------------------------------------------- launch

extern "C" void kernel_launch(void* const* d_in, const int* in_sizes, int n_in,
                              void* d_out, int out_size, void* d_ws, size_t ws_size,
                              hipStream_t stream){
  const float* x          = (const float*)d_in[0];
  const float* layer_past = (const float*)d_in[1];
  const float* c_attn_w   = (const float*)d_in[2];
  const float* c_attn_b   = (const float*)d_in[3];
  const float* c_proj_w   = (const float*)d_in[4];
  const float* c_proj_b   = (const float*)d_in[5];

  float* out = (float*)d_out;
  float* present = out + (size_t)B_*S_*NX_;   // a is [B,S,NX] = 8,388,608 f32
  float* presV = present + BHND_;

  // Kb (bf16 K cache, 21 MB) lives in the `a` region of d_out: attn reads it,
  // then gemm<1> fully overwrites all 33.5 MB of `a` -> no garbage leaks.
  unsigned short* Kb = (unsigned short*)out;

  // workspace: 20,971,520 shorts = 41.9 MiB total
  unsigned short* ws = (unsigned short*)d_ws;
  unsigned short* xb     = ws;                              // 8,388,608 (reused as Ab after gemm<0>)
  unsigned short* wqkvT  = xb     + (size_t)8388608;        // 3,145,728  [3072][1024]
  unsigned short* wprojT = wqkvT  + (size_t)3145728;        // 1,048,576  [1024][1024]
  unsigned short* Qb     = wprojT + (size_t)1048576;        // 8,388,608  [B*H][2048][64]
  unsigned short* Ab     = xb;                              // alias: xb dead after gemm<0>

  cvt_f32_bf16<<<2048, 256, 0, stream>>>(x, xb, (int)(8388608/4));
  transpose_cvt<<<dim3(3072/32, 1024/32), 256, 0, stream>>>(c_attn_w, wqkvT, 1024, 3072);
  transpose_cvt<<<dim3(1024/32, 1024/32), 256, 0, stream>>>(c_proj_w, wprojT, 1024, 1024);
  past_kernel<<<2048, 256, 0, stream>>>(layer_past, present, Kb);

  gemm_bf16<0><<<dim3(64, 24), 256, 0, stream>>>(xb, wqkvT, c_attn_b, 1024, 3072,
                                                 nullptr, Qb, Kb, present);
  attn_kernel<<<dim3(16, 64), 256, 0, stream>>>(Qb, Kb, presV, Ab);
  gemm_bf16<1><<<dim3(64, 8), 256, 0, stream>>>(Ab, wprojT, c_proj_b, 1024, 1024,
                                                out, nullptr, nullptr, nullptr);
}

// Round 7
// 416.736 us; speedup vs baseline: 1.4611x; 1.1356x over previous
//
#include <hip/hip_runtime.h>

#define B_  4
#define S_  2048
#define NX_ 1024
#define H_  16
#define D_  64
#define P_  512
#define NS_ 2560   // P + S
#define BHND_ ((size_t)B_*H_*NS_*D_)   // 10,485,760

#define QSCALE_ 0.18033688011112042f   // 0.125 * log2(e)
#define MASKC_  -14426.950408889634f   // -10000 * log2(e)

typedef __attribute__((ext_vector_type(8))) short bf16x8;
typedef __attribute__((ext_vector_type(4))) float f32x4;
typedef __attribute__((ext_vector_type(4))) float float4v;
typedef __attribute__((ext_vector_type(4))) unsigned short ushort4v;
typedef __attribute__((ext_vector_type(4))) unsigned int u32x4;

__device__ __forceinline__ unsigned short f2bf(float f){
  union { float f; unsigned u; } v; v.f = f;
  unsigned r = v.u + 0x7FFFu + ((v.u >> 16) & 1u);
  return (unsigned short)(r >> 16);
}

// pack two f32 -> u32 of 2 bf16 (RNE), lo = first arg
__device__ __forceinline__ unsigned cvtpk(float lo, float hi){
  unsigned r;
  asm("v_cvt_pk_bf16_f32 %0, %1, %2" : "=v"(r) : "v"(lo), "v"(hi));
  return r;
}

__device__ __forceinline__ void gll16(const void* g, void* l){
  __builtin_amdgcn_global_load_lds(
      (const __attribute__((address_space(1))) unsigned int*)g,
      (__attribute__((address_space(3))) unsigned int*)l, 16, 0, 0);
}

// barrier that drains LDS ops but leaves global (prefetch) loads in flight
__device__ __forceinline__ void bar_nodrain(){
  __builtin_amdgcn_sched_barrier(0);
  asm volatile("s_waitcnt lgkmcnt(0)" ::: "memory");
  __builtin_amdgcn_s_barrier();
  __builtin_amdgcn_sched_barrier(0);
}

// ---------------------------------------------------------------- prep kernels

__global__ void cvt_f32_bf16(const float* __restrict__ in, unsigned short* __restrict__ out, int n4){
  for (int i = blockIdx.x*blockDim.x + threadIdx.x; i < n4; i += gridDim.x*blockDim.x){
    float4v v = ((const float4v*)in)[i];
    ushort4v u = { f2bf(v.x), f2bf(v.y), f2bf(v.z), f2bf(v.w) };
    ((ushort4v*)out)[i] = u;
  }
}

// out[n][k] = bf16(in[k][n]); in: [K][N] f32
__global__ void transpose_cvt(const float* __restrict__ in, unsigned short* __restrict__ out, int K, int N){
  __shared__ float tile[32][33];
  int n0 = blockIdx.x*32, k0 = blockIdx.y*32;
  int tx = threadIdx.x & 31, ty = threadIdx.x >> 5;   // 256 thr = 32x8
  #pragma unroll
  for (int r = 0; r < 32; r += 8)
    tile[ty + r][tx] = in[(size_t)(k0 + ty + r)*N + n0 + tx];
  __syncthreads();
  #pragma unroll
  for (int r = 0; r < 32; r += 8)
    out[(size_t)(n0 + ty + r)*K + k0 + tx] = f2bf(tile[tx][ty + r]);
}

// layer_past -> present positions 0..511 (f32 exact) + Kb bf16 (K half only)
__global__ void past_kernel(const float* __restrict__ past, float* __restrict__ present,
                            unsigned short* __restrict__ Kb){
  const int total4 = 2*B_*H_*P_*D_/4;  // 1,048,576 float4s
  for (int i = blockIdx.x*blockDim.x + threadIdx.x; i < total4; i += gridDim.x*blockDim.x){
    int d4  = i & 15;
    int pos = (i >> 4) & 511;
    int h   = (i >> 13) & 15;
    int b   = (i >> 17) & 3;
    int kv  = i >> 19;
    float4v v = ((const float4v*)past)[i];
    size_t off = (((size_t)(b*H_ + h))*NS_ + pos)*D_ + d4*4;
    ((float4v*)present)[((size_t)kv*BHND_ + off) >> 2] = v;
    if (!kv){
      ushort4v u = { f2bf(v.x), f2bf(v.y), f2bf(v.z), f2bf(v.w) };
      ((ushort4v*)Kb)[off >> 2] = u;
    }
  }
}

// ---------------------------------------------------------------- GEMM (m97-style 128x128, BK=32)
template<int EPI>
__global__ __launch_bounds__(256, 2) void gemm_bf16(
    const unsigned short* __restrict__ A,
    const unsigned short* __restrict__ Bt,
    const float* __restrict__ bias,
    const int K, const int N,
    float* __restrict__ out_f32,
    unsigned short* __restrict__ out_q,
    unsigned short* __restrict__ out_k,
    float* __restrict__ present)
{
  __shared__ unsigned short As[128*32];  // 8 KB, [m][k] linear, 64B rows
  __shared__ unsigned short Bs[128*32];
  const int bm = blockIdx.x, bn = blockIdx.y;
  const int tid = threadIdx.x, lane = tid & 63, w = tid >> 6;
  const int wr = w >> 1, wc = w & 1;
  const int g = lane >> 4, li = lane & 15;
  f32x4 acc[4][4] = {};
  const char* Ab = (const char*)A + (size_t)(bm*128)*(K*2);
  const char* Bb = (const char*)Bt + (size_t)(bn*128)*(K*2);

  for (int kt = 0; kt < K; kt += 32){
    #pragma unroll
    for (int c = 0; c < 2; ++c){
      int off = c*4096 + w*1024 + lane*16;  // linear byte offset in 8KB tile
      int row = off >> 6, col = off & 63;
      gll16(Ab + (size_t)row*(K*2) + (size_t)kt*2 + col, (char*)As + c*4096 + w*1024);
      gll16(Bb + (size_t)row*(K*2) + (size_t)kt*2 + col, (char*)Bs + c*4096 + w*1024);
    }
    __syncthreads();
    bf16x8 af[4], bfr[4];
    #pragma unroll
    for (int mf = 0; mf < 4; ++mf)
      af[mf] = *(const bf16x8*)((const char*)As + (wr*64 + mf*16 + li)*64 + g*16);
    #pragma unroll
    for (int nf = 0; nf < 4; ++nf)
      bfr[nf] = *(const bf16x8*)((const char*)Bs + (wc*64 + nf*16 + li)*64 + g*16);
    #pragma unroll
    for (int mf = 0; mf < 4; ++mf)
      #pragma unroll
      for (int nf = 0; nf < 4; ++nf)
        acc[mf][nf] = __builtin_amdgcn_mfma_f32_16x16x32_bf16(af[mf], bfr[nf], acc[mf][nf], 0, 0, 0);
    __syncthreads();
  }

  #pragma unroll
  for (int mf = 0; mf < 4; ++mf){
    #pragma unroll
    for (int nf = 0; nf < 4; ++nf){
      int n = bn*128 + wc*64 + nf*16 + li;
      float bsv = bias[n];
      #pragma unroll
      for (int r = 0; r < 4; ++r){
        int m = bm*128 + wr*64 + mf*16 + g*4 + r;
        float v = acc[mf][nf][r] + bsv;
        if (EPI == 0){
          int b = m >> 11, sI = m & 2047;
          if (n < 1024){
            int hh = n >> 6, d = n & 63;
            out_q[(((size_t)(b*H_ + hh)*S_ + sI) << 6) + d] = f2bf(v * QSCALE_);
          } else {
            int cc = n & 1023; int hh = cc >> 6, d = cc & 63;
            size_t off = (((size_t)(b*H_ + hh)*NS_ + P_ + sI) << 6) + d;
            if (n < 2048){
              present[off] = v;
              out_k[off] = f2bf(v);
            } else {
              present[BHND_ + off] = v;
            }
          }
        } else {
          out_f32[(size_t)m*N + n] = v;
        }
      }
    }
  }
}

// ---------------------------------------------------------------- flash attention
// grid (64 bh, 8 pairs); 256 threads = 4 waves x 32 q-rows; KV tile 64.
// Each block processes supertiles (15-pa) then (pa): nt sums to 50 for every block
// -> 512 identical blocks = exactly 2 independent blocks per CU (cross-block latency
// overlap, no per-CU imbalance). bh-fast grid => XCD = bh mod 8 (L2 locality).
// K bf16 via global_load_lds (pre-swizzled source, dbuf); V f32 reg-prefetched +
// cvt_pk. l-row via MFMA(ones). Defer-max (log2, THR=8).
__global__ __launch_bounds__(256, 3) void attn_kernel(
    const unsigned short* __restrict__ Qb,   // [B*H][2048][64] bf16, pre-scaled by QSCALE_
    const unsigned short* __restrict__ Kb,   // [B*H][2560][64] bf16
    const float* __restrict__ presV,         // [B*H][2560][64] f32
    unsigned short* __restrict__ Aout)       // [B][2048][1024] bf16
{
  __shared__ unsigned short Klds[2][64*64];  // 2 x 8 KB, XOR-swizzled rows (128B)
  __shared__ unsigned short Vt[64*72];       // [d][kv-slots], row stride 144B
  __shared__ unsigned short Plds[4][32*72];  // per-wave [q][kv-permuted], 144B rows

  const int bh = blockIdx.x;
  const int pa = blockIdx.y;                 // 0..7
  const int tid = threadIdx.x, lane = tid & 63, w = tid >> 6;
  const int g = lane >> 4, li = lane & 15;

  // K gll staging: 2 chunks of 16B per thread, pre-swizzled global source
  const int koff0 = w*1024 + lane*16;            // c=0
  const int koff1 = 4096 + w*1024 + lane*16;     // c=1
  const char* KbB = (const char*)Kb + (((size_t)bh*NS_) << 7);
  const char* pK0 = KbB + (size_t)(koff0 >> 7)*128 + (((koff0 & 127) ^ (((koff0 >> 7) & 7) << 4)));
  const char* pK1 = KbB + (size_t)(koff1 >> 7)*128 + (((koff1 & 127) ^ (((koff1 >> 7) & 7) << 4)));

  // V staging coords
  const int vslot = tid & 31, vd0 = (tid >> 5) << 3;     // V: u32 slot, 8 d-values
  const int vkv_lo = (vslot & 15) + ((vslot >> 4) << 5); // slot -> (kv_lo, kv_lo+16)
  const float* Vbase = presV + (((size_t)bh*NS_) << 6);
  const int b = bh >> 4, h = bh & 15;

  // ones B-fragment for l-row MFMA
  bf16x8 ones;
  #pragma unroll
  for (int j = 0; j < 8; ++j) ones[j] = (short)0x3F80;

  #pragma unroll 1
  for (int seg = 0; seg < 2; ++seg){
    const int qsup = seg ? pa : (15 - pa);
    const int nt = 2*qsup + 10;
    const int q0w = qsup*128 + w*32;

    // all waves done with Klds/Vt of the previous segment before re-staging
    bar_nodrain();

    // Q fragments: rows q0w+rf*16+li, k-slices of 8
    bf16x8 qf[2][2];
    #pragma unroll
    for (int rf = 0; rf < 2; ++rf)
      #pragma unroll
      for (int ks = 0; ks < 2; ++ks)
        qf[rf][ks] = *(const bf16x8*)(Qb + (((size_t)bh*S_ + q0w + rf*16 + li) << 6) + ks*32 + g*8);

    f32x4 o[2][4];
    f32x4 lacc[2];
    float mrow[2][4];
    #pragma unroll
    for (int rf = 0; rf < 2; ++rf){
      #pragma unroll
      for (int df = 0; df < 4; ++df) o[rf][df] = (f32x4){0.f,0.f,0.f,0.f};
      lacc[rf] = (f32x4){0.f,0.f,0.f,0.f};
      #pragma unroll
      for (int r = 0; r < 4; ++r) mrow[rf][r] = -1e30f;
    }

    // prologue: gll K(0) FIRST, then raw V(0) loads (vmcnt order => V-wait covers gll)
    float4v vraw[4];
    {
      gll16(pK0, (char*)Klds[0] + w*1024);
      gll16(pK1, (char*)Klds[0] + 4096 + w*1024);
      __builtin_amdgcn_sched_barrier(0);
      const float* vl = Vbase + ((size_t)vkv_lo << 6) + vd0;
      vraw[0] = ((const float4v*)vl)[0]; vraw[1] = ((const float4v*)vl)[1];
      const float* vh = vl + (16 << 6);
      vraw[2] = ((const float4v*)vh)[0]; vraw[3] = ((const float4v*)vh)[1];
    }

    #pragma unroll 1
    for (int t = 0; t < nt; ++t){
      const int cur = t & 1;
      // a) convert V raw -> packed bf16 (implicit vmcnt wait: also guarantees K gll landed)
      unsigned vu[8];
      {
        const float* vlo = (const float*)&vraw[0];
        const float* vhi = (const float*)&vraw[2];
        #pragma unroll
        for (int j = 0; j < 8; ++j) vu[j] = cvtpk(vlo[j], vhi[j]);
      }
      // b) prev tile's LDS reads done
      bar_nodrain();
      // c) stage V (permuted kv-pair slots, 8 b32 writes)
      #pragma unroll
      for (int j = 0; j < 8; ++j)
        *(unsigned*)((char*)Vt + (size_t)(vd0 + j)*144 + vslot*4) = vu[j];
      // d) issue next tile: K gll FIRST, then raw V loads
      if (t + 1 < nt){
        size_t adv = (size_t)(t + 1) * 8192;
        gll16(pK0 + adv, (char*)Klds[cur ^ 1] + w*1024);
        gll16(pK1 + adv, (char*)Klds[cur ^ 1] + 4096 + w*1024);
        __builtin_amdgcn_sched_barrier(0);
        const float* vl = Vbase + ((size_t)((t+1)*64 + vkv_lo) << 6) + vd0;
        vraw[0] = ((const float4v*)vl)[0]; vraw[1] = ((const float4v*)vl)[1];
        const float* vh = vl + (16 << 6);
        vraw[2] = ((const float4v*)vh)[0]; vraw[3] = ((const float4v*)vh)[1];
      }
      // e) staged LDS visible; next-tile loads stay in flight
      bar_nodrain();

      const int kbase = t*64;
      if (kbase <= q0w + 543){                      // wave has any unmasked key in this tile
        const bool needmask = (kbase + 63) > (q0w + 512);

        // --- S = Q K^T (log2-scaled since Q pre-scaled) ---
        f32x4 s[2][4];
        #pragma unroll
        for (int cf = 0; cf < 4; ++cf){
          int row = cf*16 + li;
          int sw = (row & 7) << 4;
          const char* kb = (const char*)Klds[cur] + row*128;
          bf16x8 bk0 = *(const bf16x8*)(kb + ((g*16) ^ sw));
          bf16x8 bk1 = *(const bf16x8*)(kb + ((64 + g*16) ^ sw));
          #pragma unroll
          for (int rf = 0; rf < 2; ++rf){
            f32x4 a0 = (f32x4){0.f,0.f,0.f,0.f};
            a0 = __builtin_amdgcn_mfma_f32_16x16x32_bf16(qf[rf][0], bk0, a0, 0, 0, 0);
            a0 = __builtin_amdgcn_mfma_f32_16x16x32_bf16(qf[rf][1], bk1, a0, 0, 0, 0);
            s[rf][cf] = a0;
          }
        }

        #pragma unroll
        for (int rf = 0; rf < 2; ++rf){
          float pm[4];
          #pragma unroll
          for (int r = 0; r < 4; ++r){
            if (needmask){
              int q = q0w + rf*16 + g*4 + r;
              int lim = q + 512 - kbase;            // key_local <= lim allowed
              #pragma unroll
              for (int cf = 0; cf < 4; ++cf){
                int kl = cf*16 + li;
                s[rf][cf][r] = (kl <= lim) ? s[rf][cf][r] : MASKC_;
              }
            }
            pm[r] = fmaxf(fmaxf(s[rf][0][r], s[rf][1][r]), fmaxf(s[rf][2][r], s[rf][3][r]));
          }
          #pragma unroll
          for (int r = 0; r < 4; ++r)
            #pragma unroll
            for (int d2 = 1; d2 < 16; d2 <<= 1)
              pm[r] = fmaxf(pm[r], __shfl_xor(pm[r], d2, 64));

          // defer-max: only rescale when max grew by > 8 (log2 domain, P <= 256)
          bool grow = (pm[0] > mrow[rf][0] + 8.f) | (pm[1] > mrow[rf][1] + 8.f) |
                      (pm[2] > mrow[rf][2] + 8.f) | (pm[3] > mrow[rf][3] + 8.f);
          if (__ballot(grow)){
            #pragma unroll
            for (int r = 0; r < 4; ++r){
              float mn = fmaxf(mrow[rf][r], pm[r]);
              float al = __builtin_amdgcn_exp2f(mrow[rf][r] - mn);
              mrow[rf][r] = mn;
              #pragma unroll
              for (int df = 0; df < 4; ++df) o[rf][df][r] *= al;
              lacc[rf][r] *= al;
            }
          }

          // P = exp2(S - m), packed pairs -> permuted layout
          #pragma unroll
          for (int r = 0; r < 4; ++r){
            float p0 = __builtin_amdgcn_exp2f(s[rf][0][r] - mrow[rf][r]);
            float p1 = __builtin_amdgcn_exp2f(s[rf][1][r] - mrow[rf][r]);
            float p2 = __builtin_amdgcn_exp2f(s[rf][2][r] - mrow[rf][r]);
            float p3 = __builtin_amdgcn_exp2f(s[rf][3][r] - mrow[rf][r]);
            char* prow = (char*)Plds[w] + (size_t)(rf*16 + g*4 + r)*144 + li*4;
            *(unsigned*)prow        = cvtpk(p0, p1);
            *(unsigned*)(prow + 64) = cvtpk(p2, p3);
          }
        }

        // --- O += P V ;  l += P * ones  (MFMA pipe) ---
        bf16x8 bv[4][2];
        #pragma unroll
        for (int df = 0; df < 4; ++df){
          bv[df][0] = *(const bf16x8*)(Vt + (df*16 + li)*72 + g*8);
          bv[df][1] = *(const bf16x8*)(Vt + (df*16 + li)*72 + 32 + g*8);
        }
        #pragma unroll
        for (int rf = 0; rf < 2; ++rf){
          bf16x8 pa0 = *(const bf16x8*)(Plds[w] + (rf*16 + li)*72 + g*8);
          bf16x8 pa1 = *(const bf16x8*)(Plds[w] + (rf*16 + li)*72 + 32 + g*8);
          #pragma unroll
          for (int df = 0; df < 4; ++df){
            o[rf][df] = __builtin_amdgcn_mfma_f32_16x16x32_bf16(pa0, bv[df][0], o[rf][df], 0, 0, 0);
            o[rf][df] = __builtin_amdgcn_mfma_f32_16x16x32_bf16(pa1, bv[df][1], o[rf][df], 0, 0, 0);
          }
          lacc[rf] = __builtin_amdgcn_mfma_f32_16x16x32_bf16(pa0, ones, lacc[rf], 0, 0, 0);
          lacc[rf] = __builtin_amdgcn_mfma_f32_16x16x32_bf16(pa1, ones, lacc[rf], 0, 0, 0);
        }
      }
    }

    // --- segment epilogue ---
    #pragma unroll
    for (int rf = 0; rf < 2; ++rf){
      float inv[4];
      #pragma unroll
      for (int r = 0; r < 4; ++r) inv[r] = 1.0f / lacc[rf][r];
      #pragma unroll
      for (int df = 0; df < 4; ++df)
        #pragma unroll
        for (int r = 0; r < 4; ++r){
          int q = q0w + rf*16 + g*4 + r;
          Aout[((size_t)b*S_ + q)*NX_ + h*64 + df*16 + li] = f2bf(o[rf][df][r]*inv[r]);
        }
    }
  }
}

// ---------------------------------------------------------------- launch

extern "C" void kernel_launch(void* const* d_in, const int* in_sizes, int n_in,
                              void* d_out, int out_size, void* d_ws, size_t ws_size,
                              hipStream_t stream){
  const float* x          = (const float*)d_in[0];
  const float* layer_past = (const float*)d_in[1];
  const float* c_attn_w   = (const float*)d_in[2];
  const float* c_attn_b   = (const float*)d_in[3];
  const float* c_proj_w   = (const float*)d_in[4];
  const float* c_proj_b   = (const float*)d_in[5];

  float* out = (float*)d_out;
  float* present = out + (size_t)B_*S_*NX_;   // a is [B,S,NX] = 8,388,608 f32
  float* presV = present + BHND_;

  // Kb (bf16 K cache, 21 MB) lives in the `a` region of d_out: attn reads it,
  // then gemm<1> fully overwrites all 33.5 MB of `a` -> no garbage leaks.
  unsigned short* Kb = (unsigned short*)out;

  // workspace: 20,971,520 shorts = 41.9 MiB total
  unsigned short* ws = (unsigned short*)d_ws;
  unsigned short* xb     = ws;                              // 8,388,608 (reused as Ab after gemm<0>)
  unsigned short* wqkvT  = xb     + (size_t)8388608;        // 3,145,728  [3072][1024]
  unsigned short* wprojT = wqkvT  + (size_t)3145728;        // 1,048,576  [1024][1024]
  unsigned short* Qb     = wprojT + (size_t)1048576;        // 8,388,608  [B*H][2048][64]
  unsigned short* Ab     = xb;                              // alias: xb dead after gemm<0>

  cvt_f32_bf16<<<2048, 256, 0, stream>>>(x, xb, (int)(8388608/4));
  transpose_cvt<<<dim3(3072/32, 1024/32), 256, 0, stream>>>(c_attn_w, wqkvT, 1024, 3072);
  transpose_cvt<<<dim3(1024/32, 1024/32), 256, 0, stream>>>(c_proj_w, wprojT, 1024, 1024);
  past_kernel<<<2048, 256, 0, stream>>>(layer_past, present, Kb);

  gemm_bf16<0><<<dim3(64, 24), 256, 0, stream>>>(xb, wqkvT, c_attn_b, 1024, 3072,
                                                 nullptr, Qb, Kb, present);
  attn_kernel<<<dim3(64, 8), 256, 0, stream>>>(Qb, Kb, presV, Ab);
  gemm_bf16<1><<<dim3(64, 8), 256, 0, stream>>>(Ab, wprojT, c_proj_b, 1024, 1024,
                                                out, nullptr, nullptr, nullptr);
}

// Round 8
// 378.109 us; speedup vs baseline: 1.6104x; 1.1022x over previous
//
#include <hip/hip_runtime.h>

#define B_  4
#define S_  2048
#define NX_ 1024
#define H_  16
#define D_  64
#define P_  512
#define NS_ 2560   // P + S
#define BHND_ ((size_t)B_*H_*NS_*D_)   // 10,485,760

#define QSCALE_ 0.18033688011112042f   // 0.125 * log2(e)
#define MASKC_  -14426.950408889634f   // -10000 * log2(e)

typedef __attribute__((ext_vector_type(8))) short bf16x8;
typedef __attribute__((ext_vector_type(4))) float f32x4;
typedef __attribute__((ext_vector_type(4))) float float4v;
typedef __attribute__((ext_vector_type(4))) unsigned short ushort4v;
typedef __attribute__((ext_vector_type(4))) unsigned int u32x4;

__device__ __forceinline__ unsigned short f2bf(float f){
  union { float f; unsigned u; } v; v.f = f;
  unsigned r = v.u + 0x7FFFu + ((v.u >> 16) & 1u);
  return (unsigned short)(r >> 16);
}

// pack two f32 -> u32 of 2 bf16 (RNE), lo = first arg
__device__ __forceinline__ unsigned cvtpk(float lo, float hi){
  unsigned r;
  asm("v_cvt_pk_bf16_f32 %0, %1, %2" : "=v"(r) : "v"(lo), "v"(hi));
  return r;
}

__device__ __forceinline__ void gll16(const void* g, void* l){
  __builtin_amdgcn_global_load_lds(
      (const __attribute__((address_space(1))) unsigned int*)g,
      (__attribute__((address_space(3))) unsigned int*)l, 16, 0, 0);
}

// barrier that drains LDS ops but leaves global (prefetch) loads in flight
__device__ __forceinline__ void bar_nodrain(){
  __builtin_amdgcn_sched_barrier(0);
  asm volatile("s_waitcnt lgkmcnt(0)" ::: "memory");
  __builtin_amdgcn_s_barrier();
  __builtin_amdgcn_sched_barrier(0);
}

// ---------------------------------------------------------------- prep kernels

__global__ void cvt_f32_bf16(const float* __restrict__ in, unsigned short* __restrict__ out, int n4){
  for (int i = blockIdx.x*blockDim.x + threadIdx.x; i < n4; i += gridDim.x*blockDim.x){
    float4v v = ((const float4v*)in)[i];
    ushort4v u = { f2bf(v.x), f2bf(v.y), f2bf(v.z), f2bf(v.w) };
    ((ushort4v*)out)[i] = u;
  }
}

// out[n][k] = bf16(in[k][n]); in: [K][N] f32
__global__ void transpose_cvt(const float* __restrict__ in, unsigned short* __restrict__ out, int K, int N){
  __shared__ float tile[32][33];
  int n0 = blockIdx.x*32, k0 = blockIdx.y*32;
  int tx = threadIdx.x & 31, ty = threadIdx.x >> 5;   // 256 thr = 32x8
  #pragma unroll
  for (int r = 0; r < 32; r += 8)
    tile[ty + r][tx] = in[(size_t)(k0 + ty + r)*N + n0 + tx];
  __syncthreads();
  #pragma unroll
  for (int r = 0; r < 32; r += 8)
    out[(size_t)(n0 + ty + r)*K + k0 + tx] = f2bf(tile[tx][ty + r]);
}

// layer_past -> present positions 0..511 (f32 exact) + Kb bf16 (K half only)
__global__ void past_kernel(const float* __restrict__ past, float* __restrict__ present,
                            unsigned short* __restrict__ Kb){
  const int total4 = 2*B_*H_*P_*D_/4;  // 1,048,576 float4s
  for (int i = blockIdx.x*blockDim.x + threadIdx.x; i < total4; i += gridDim.x*blockDim.x){
    int d4  = i & 15;
    int pos = (i >> 4) & 511;
    int h   = (i >> 13) & 15;
    int b   = (i >> 17) & 3;
    int kv  = i >> 19;
    float4v v = ((const float4v*)past)[i];
    size_t off = (((size_t)(b*H_ + h))*NS_ + pos)*D_ + d4*4;
    ((float4v*)present)[((size_t)kv*BHND_ + off) >> 2] = v;
    if (!kv){
      ushort4v u = { f2bf(v.x), f2bf(v.y), f2bf(v.z), f2bf(v.w) };
      ((ushort4v*)Kb)[off >> 2] = u;
    }
  }
}

// ---------------------------------------------------------------- GEMM (m97-style 128x128, BK=32)
template<int EPI>
__global__ __launch_bounds__(256, 2) void gemm_bf16(
    const unsigned short* __restrict__ A,
    const unsigned short* __restrict__ Bt,
    const float* __restrict__ bias,
    const int K, const int N,
    float* __restrict__ out_f32,
    unsigned short* __restrict__ out_q,
    unsigned short* __restrict__ out_k,
    float* __restrict__ present)
{
  __shared__ unsigned short As[128*32];  // 8 KB, [m][k] linear, 64B rows
  __shared__ unsigned short Bs[128*32];
  const int bm = blockIdx.x, bn = blockIdx.y;
  const int tid = threadIdx.x, lane = tid & 63, w = tid >> 6;
  const int wr = w >> 1, wc = w & 1;
  const int g = lane >> 4, li = lane & 15;
  f32x4 acc[4][4] = {};
  const char* Ab = (const char*)A + (size_t)(bm*128)*(K*2);
  const char* Bb = (const char*)Bt + (size_t)(bn*128)*(K*2);

  for (int kt = 0; kt < K; kt += 32){
    #pragma unroll
    for (int c = 0; c < 2; ++c){
      int off = c*4096 + w*1024 + lane*16;  // linear byte offset in 8KB tile
      int row = off >> 6, col = off & 63;
      gll16(Ab + (size_t)row*(K*2) + (size_t)kt*2 + col, (char*)As + c*4096 + w*1024);
      gll16(Bb + (size_t)row*(K*2) + (size_t)kt*2 + col, (char*)Bs + c*4096 + w*1024);
    }
    __syncthreads();
    bf16x8 af[4], bfr[4];
    #pragma unroll
    for (int mf = 0; mf < 4; ++mf)
      af[mf] = *(const bf16x8*)((const char*)As + (wr*64 + mf*16 + li)*64 + g*16);
    #pragma unroll
    for (int nf = 0; nf < 4; ++nf)
      bfr[nf] = *(const bf16x8*)((const char*)Bs + (wc*64 + nf*16 + li)*64 + g*16);
    #pragma unroll
    for (int mf = 0; mf < 4; ++mf)
      #pragma unroll
      for (int nf = 0; nf < 4; ++nf)
        acc[mf][nf] = __builtin_amdgcn_mfma_f32_16x16x32_bf16(af[mf], bfr[nf], acc[mf][nf], 0, 0, 0);
    __syncthreads();
  }

  #pragma unroll
  for (int mf = 0; mf < 4; ++mf){
    #pragma unroll
    for (int nf = 0; nf < 4; ++nf){
      int n = bn*128 + wc*64 + nf*16 + li;
      float bsv = bias[n];
      #pragma unroll
      for (int r = 0; r < 4; ++r){
        int m = bm*128 + wr*64 + mf*16 + g*4 + r;
        float v = acc[mf][nf][r] + bsv;
        if (EPI == 0){
          int b = m >> 11, sI = m & 2047;
          if (n < 1024){
            int hh = n >> 6, d = n & 63;
            out_q[(((size_t)(b*H_ + hh)*S_ + sI) << 6) + d] = f2bf(v * QSCALE_);
          } else {
            int cc = n & 1023; int hh = cc >> 6, d = cc & 63;
            size_t off = (((size_t)(b*H_ + hh)*NS_ + P_ + sI) << 6) + d;
            if (n < 2048){
              present[off] = v;
              out_k[off] = f2bf(v);
            } else {
              present[BHND_ + off] = v;
            }
          }
        } else {
          out_f32[(size_t)m*N + n] = v;
        }
      }
    }
  }
}

// ---------------------------------------------------------------- flash attention
// grid (64 bh, 16 qsup); 256 threads = 4 waves x 32 q-rows; KV tile 64.
// One supertile per block; qsup = 15 - blockIdx.y so 40-tile blocks dispatch first
// (LPT backfill). 1024 blocks -> 3 blocks/CU resident (LB(256,3), LDS 43KBx3=129KB).
// bh-fast grid => XCD = bh mod 8 (L2 locality). K bf16 via global_load_lds
// (pre-swizzled source, dbuf); V f32 reg-prefetched + cvt_pk. l-row via MFMA(ones).
// Defer-max (log2, THR=8).
__global__ __launch_bounds__(256, 3) void attn_kernel(
    const unsigned short* __restrict__ Qb,   // [B*H][2048][64] bf16, pre-scaled by QSCALE_
    const unsigned short* __restrict__ Kb,   // [B*H][2560][64] bf16
    const float* __restrict__ presV,         // [B*H][2560][64] f32
    unsigned short* __restrict__ Aout)       // [B][2048][1024] bf16
{
  __shared__ unsigned short Klds[2][64*64];  // 2 x 8 KB, XOR-swizzled rows (128B)
  __shared__ unsigned short Vt[64*72];       // [d][kv-slots], row stride 144B
  __shared__ unsigned short Plds[4][32*72];  // per-wave [q][kv-permuted], 144B rows

  const int bh = blockIdx.x;
  const int qsup = 15 - (int)blockIdx.y;     // long blocks first (LPT backfill)
  const int tid = threadIdx.x, lane = tid & 63, w = tid >> 6;
  const int g = lane >> 4, li = lane & 15;
  const int q0w = qsup*128 + w*32;
  const int nt = 2*qsup + 10;

  // K gll staging: 2 chunks of 16B per thread, pre-swizzled global source
  const int koff0 = w*1024 + lane*16;            // c=0
  const int koff1 = 4096 + w*1024 + lane*16;     // c=1
  const char* KbB = (const char*)Kb + (((size_t)bh*NS_) << 7);
  const char* pK0 = KbB + (size_t)(koff0 >> 7)*128 + (((koff0 & 127) ^ (((koff0 >> 7) & 7) << 4)));
  const char* pK1 = KbB + (size_t)(koff1 >> 7)*128 + (((koff1 & 127) ^ (((koff1 >> 7) & 7) << 4)));

  // V staging coords
  const int vslot = tid & 31, vd0 = (tid >> 5) << 3;     // V: u32 slot, 8 d-values
  const int vkv_lo = (vslot & 15) + ((vslot >> 4) << 5); // slot -> (kv_lo, kv_lo+16)
  const float* Vbase = presV + (((size_t)bh*NS_) << 6);
  const int b = bh >> 4, h = bh & 15;

  // ones B-fragment for l-row MFMA
  bf16x8 ones;
  #pragma unroll
  for (int j = 0; j < 8; ++j) ones[j] = (short)0x3F80;

  // Q fragments: rows q0w+rf*16+li, k-slices of 8
  bf16x8 qf[2][2];
  #pragma unroll
  for (int rf = 0; rf < 2; ++rf)
    #pragma unroll
    for (int ks = 0; ks < 2; ++ks)
      qf[rf][ks] = *(const bf16x8*)(Qb + (((size_t)bh*S_ + q0w + rf*16 + li) << 6) + ks*32 + g*8);

  f32x4 o[2][4];
  f32x4 lacc[2];
  float mrow[2][4];
  #pragma unroll
  for (int rf = 0; rf < 2; ++rf){
    #pragma unroll
    for (int df = 0; df < 4; ++df) o[rf][df] = (f32x4){0.f,0.f,0.f,0.f};
    lacc[rf] = (f32x4){0.f,0.f,0.f,0.f};
    #pragma unroll
    for (int r = 0; r < 4; ++r) mrow[rf][r] = -1e30f;
  }

  // prologue: gll K(0) FIRST, then raw V(0) loads (vmcnt order => V-wait covers gll)
  float4v vraw[4];
  {
    gll16(pK0, (char*)Klds[0] + w*1024);
    gll16(pK1, (char*)Klds[0] + 4096 + w*1024);
    __builtin_amdgcn_sched_barrier(0);
    const float* vl = Vbase + ((size_t)vkv_lo << 6) + vd0;
    vraw[0] = ((const float4v*)vl)[0]; vraw[1] = ((const float4v*)vl)[1];
    const float* vh = vl + (16 << 6);
    vraw[2] = ((const float4v*)vh)[0]; vraw[3] = ((const float4v*)vh)[1];
  }

  #pragma unroll 1
  for (int t = 0; t < nt; ++t){
    const int cur = t & 1;
    // a) convert V raw -> packed bf16 (implicit vmcnt wait: also guarantees K gll landed)
    unsigned vu[8];
    {
      const float* vlo = (const float*)&vraw[0];
      const float* vhi = (const float*)&vraw[2];
      #pragma unroll
      for (int j = 0; j < 8; ++j) vu[j] = cvtpk(vlo[j], vhi[j]);
    }
    // b) prev tile's LDS reads done
    bar_nodrain();
    // c) stage V (permuted kv-pair slots, 8 b32 writes)
    #pragma unroll
    for (int j = 0; j < 8; ++j)
      *(unsigned*)((char*)Vt + (size_t)(vd0 + j)*144 + vslot*4) = vu[j];
    // d) issue next tile: K gll FIRST, then raw V loads
    if (t + 1 < nt){
      size_t adv = (size_t)(t + 1) * 8192;
      gll16(pK0 + adv, (char*)Klds[cur ^ 1] + w*1024);
      gll16(pK1 + adv, (char*)Klds[cur ^ 1] + 4096 + w*1024);
      __builtin_amdgcn_sched_barrier(0);
      const float* vl = Vbase + ((size_t)((t+1)*64 + vkv_lo) << 6) + vd0;
      vraw[0] = ((const float4v*)vl)[0]; vraw[1] = ((const float4v*)vl)[1];
      const float* vh = vl + (16 << 6);
      vraw[2] = ((const float4v*)vh)[0]; vraw[3] = ((const float4v*)vh)[1];
    }
    // e) staged LDS visible; next-tile loads stay in flight
    bar_nodrain();

    const int kbase = t*64;
    if (kbase <= q0w + 543){                      // wave has any unmasked key in this tile
      const bool needmask = (kbase + 63) > (q0w + 512);

      // --- S = Q K^T (log2-scaled since Q pre-scaled) ---
      f32x4 s[2][4];
      #pragma unroll
      for (int cf = 0; cf < 4; ++cf){
        int row = cf*16 + li;
        int sw = (row & 7) << 4;
        const char* kb = (const char*)Klds[cur] + row*128;
        bf16x8 bk0 = *(const bf16x8*)(kb + ((g*16) ^ sw));
        bf16x8 bk1 = *(const bf16x8*)(kb + ((64 + g*16) ^ sw));
        #pragma unroll
        for (int rf = 0; rf < 2; ++rf){
          f32x4 a0 = (f32x4){0.f,0.f,0.f,0.f};
          a0 = __builtin_amdgcn_mfma_f32_16x16x32_bf16(qf[rf][0], bk0, a0, 0, 0, 0);
          a0 = __builtin_amdgcn_mfma_f32_16x16x32_bf16(qf[rf][1], bk1, a0, 0, 0, 0);
          s[rf][cf] = a0;
        }
      }

      #pragma unroll
      for (int rf = 0; rf < 2; ++rf){
        float pm[4];
        #pragma unroll
        for (int r = 0; r < 4; ++r){
          if (needmask){
            int q = q0w + rf*16 + g*4 + r;
            int lim = q + 512 - kbase;            // key_local <= lim allowed
            #pragma unroll
            for (int cf = 0; cf < 4; ++cf){
              int kl = cf*16 + li;
              s[rf][cf][r] = (kl <= lim) ? s[rf][cf][r] : MASKC_;
            }
          }
          pm[r] = fmaxf(fmaxf(s[rf][0][r], s[rf][1][r]), fmaxf(s[rf][2][r], s[rf][3][r]));
        }
        #pragma unroll
        for (int r = 0; r < 4; ++r)
          #pragma unroll
          for (int d2 = 1; d2 < 16; d2 <<= 1)
            pm[r] = fmaxf(pm[r], __shfl_xor(pm[r], d2, 64));

        // defer-max: only rescale when max grew by > 8 (log2 domain, P <= 256)
        bool grow = (pm[0] > mrow[rf][0] + 8.f) | (pm[1] > mrow[rf][1] + 8.f) |
                    (pm[2] > mrow[rf][2] + 8.f) | (pm[3] > mrow[rf][3] + 8.f);
        if (__ballot(grow)){
          #pragma unroll
          for (int r = 0; r < 4; ++r){
            float mn = fmaxf(mrow[rf][r], pm[r]);
            float al = __builtin_amdgcn_exp2f(mrow[rf][r] - mn);
            mrow[rf][r] = mn;
            #pragma unroll
            for (int df = 0; df < 4; ++df) o[rf][df][r] *= al;
            lacc[rf][r] *= al;
          }
        }

        // P = exp2(S - m), packed pairs -> permuted layout
        #pragma unroll
        for (int r = 0; r < 4; ++r){
          float p0 = __builtin_amdgcn_exp2f(s[rf][0][r] - mrow[rf][r]);
          float p1 = __builtin_amdgcn_exp2f(s[rf][1][r] - mrow[rf][r]);
          float p2 = __builtin_amdgcn_exp2f(s[rf][2][r] - mrow[rf][r]);
          float p3 = __builtin_amdgcn_exp2f(s[rf][3][r] - mrow[rf][r]);
          char* prow = (char*)Plds[w] + (size_t)(rf*16 + g*4 + r)*144 + li*4;
          *(unsigned*)prow        = cvtpk(p0, p1);
          *(unsigned*)(prow + 64) = cvtpk(p2, p3);
        }
      }

      // --- O += P V ;  l += P * ones  (MFMA pipe) ---
      bf16x8 bv[4][2];
      #pragma unroll
      for (int df = 0; df < 4; ++df){
        bv[df][0] = *(const bf16x8*)(Vt + (df*16 + li)*72 + g*8);
        bv[df][1] = *(const bf16x8*)(Vt + (df*16 + li)*72 + 32 + g*8);
      }
      #pragma unroll
      for (int rf = 0; rf < 2; ++rf){
        bf16x8 pa0 = *(const bf16x8*)(Plds[w] + (rf*16 + li)*72 + g*8);
        bf16x8 pa1 = *(const bf16x8*)(Plds[w] + (rf*16 + li)*72 + 32 + g*8);
        #pragma unroll
        for (int df = 0; df < 4; ++df){
          o[rf][df] = __builtin_amdgcn_mfma_f32_16x16x32_bf16(pa0, bv[df][0], o[rf][df], 0, 0, 0);
          o[rf][df] = __builtin_amdgcn_mfma_f32_16x16x32_bf16(pa1, bv[df][1], o[rf][df], 0, 0, 0);
        }
        lacc[rf] = __builtin_amdgcn_mfma_f32_16x16x32_bf16(pa0, ones, lacc[rf], 0, 0, 0);
        lacc[rf] = __builtin_amdgcn_mfma_f32_16x16x32_bf16(pa1, ones, lacc[rf], 0, 0, 0);
      }
    }
  }

  // --- epilogue ---
  #pragma unroll
  for (int rf = 0; rf < 2; ++rf){
    float inv[4];
    #pragma unroll
    for (int r = 0; r < 4; ++r) inv[r] = 1.0f / lacc[rf][r];
    #pragma unroll
    for (int df = 0; df < 4; ++df)
      #pragma unroll
      for (int r = 0; r < 4; ++r){
        int q = q0w + rf*16 + g*4 + r;
        Aout[((size_t)b*S_ + q)*NX_ + h*64 + df*16 + li] = f2bf(o[rf][df][r]*inv[r]);
      }
  }
}

// ---------------------------------------------------------------- launch

extern "C" void kernel_launch(void* const* d_in, const int* in_sizes, int n_in,
                              void* d_out, int out_size, void* d_ws, size_t ws_size,
                              hipStream_t stream){
  const float* x          = (const float*)d_in[0];
  const float* layer_past = (const float*)d_in[1];
  const float* c_attn_w   = (const float*)d_in[2];
  const float* c_attn_b   = (const float*)d_in[3];
  const float* c_proj_w   = (const float*)d_in[4];
  const float* c_proj_b   = (const float*)d_in[5];

  float* out = (float*)d_out;
  float* present = out + (size_t)B_*S_*NX_;   // a is [B,S,NX] = 8,388,608 f32
  float* presV = present + BHND_;

  // Kb (bf16 K cache, 21 MB) lives in the `a` region of d_out: attn reads it,
  // then gemm<1> fully overwrites all 33.5 MB of `a` -> no garbage leaks.
  unsigned short* Kb = (unsigned short*)out;

  // workspace: 20,971,520 shorts = 41.9 MiB total
  unsigned short* ws = (unsigned short*)d_ws;
  unsigned short* xb     = ws;                              // 8,388,608 (reused as Ab after gemm<0>)
  unsigned short* wqkvT  = xb     + (size_t)8388608;        // 3,145,728  [3072][1024]
  unsigned short* wprojT = wqkvT  + (size_t)3145728;        // 1,048,576  [1024][1024]
  unsigned short* Qb     = wprojT + (size_t)1048576;        // 8,388,608  [B*H][2048][64]
  unsigned short* Ab     = xb;                              // alias: xb dead after gemm<0>

  cvt_f32_bf16<<<2048, 256, 0, stream>>>(x, xb, (int)(8388608/4));
  transpose_cvt<<<dim3(3072/32, 1024/32), 256, 0, stream>>>(c_attn_w, wqkvT, 1024, 3072);
  transpose_cvt<<<dim3(1024/32, 1024/32), 256, 0, stream>>>(c_proj_w, wprojT, 1024, 1024);
  past_kernel<<<2048, 256, 0, stream>>>(layer_past, present, Kb);

  gemm_bf16<0><<<dim3(64, 24), 256, 0, stream>>>(xb, wqkvT, c_attn_b, 1024, 3072,
                                                 nullptr, Qb, Kb, present);
  attn_kernel<<<dim3(64, 16), 256, 0, stream>>>(Qb, Kb, presV, Ab);
  gemm_bf16<1><<<dim3(64, 8), 256, 0, stream>>>(Ab, wprojT, c_proj_b, 1024, 1024,
                                                out, nullptr, nullptr, nullptr);
}